// Round 1
// baseline (116.273 us; speedup 1.0000x reference)
//
#include <hip/hip_runtime.h>

// Problem constants (from reference setup_inputs)
#define B_   8
#define CIN  8
#define COUT 32
#define H_   128
#define W_   128
#define OH   126
#define OW   126

// ---------------------------------------------------------------------------
// Kernel 1: y[b,c,i,j] = bias[c] + sum_{ci,kh,kw} x[b,ci,i+kh,j+kw]*w[c,ci,kh,kw]
// Only the first CIN=8 output channels are needed downstream.
// One thread per (b,i,j), computes all 8 channels (amortizes x loads 8x).
// Weight/bias addresses are wave-uniform -> compiler emits scalar loads.
// ---------------------------------------------------------------------------
__global__ __launch_bounds__(256) void conv_y_kernel(
    const float* __restrict__ x, const float* __restrict__ w,
    const float* __restrict__ bias, float* __restrict__ y) {
  int gid = blockIdx.x * blockDim.x + threadIdx.x;
  const int total = B_ * OH * OW;
  if (gid >= total) return;
  int j = gid % OW;
  int t2 = gid / OW;
  int i = t2 % OH;
  int b = t2 / OH;

  const float* xb = x + (long)b * CIN * H_ * W_;
  float acc[CIN];
#pragma unroll
  for (int c = 0; c < CIN; ++c) acc[c] = bias[c];

#pragma unroll
  for (int ci = 0; ci < CIN; ++ci) {
#pragma unroll
    for (int kh = 0; kh < 3; ++kh) {
      const float* xr = xb + ci * (H_ * W_) + (i + kh) * W_ + j;
      float x0 = xr[0];
      float x1 = xr[1];
      float x2 = xr[2];
#pragma unroll
      for (int c = 0; c < CIN; ++c) {
        const float* wp = w + ((c * CIN + ci) * 3 + kh) * 3;
        acc[c] = fmaf(x2, wp[2], fmaf(x1, wp[1], fmaf(x0, wp[0], acc[c])));
      }
    }
  }

  float* yp = y + (long)b * CIN * (OH * OW) + i * OW + j;
#pragma unroll
  for (int c = 0; c < CIN; ++c) yp[c * (OH * OW)] = acc[c];
}

// ---------------------------------------------------------------------------
// Kernel 2: out[b,i,j] = 2 * min_o max_{valid (kh,kw), c} y[b,c,i+kh,j+kw]*w[o,c,kh,kw]
// Tap (kh,kw) valid iff i+kh<OH and j+kw<OW (the -inf pad in the reference).
// Taps loaded once into 72 registers (static indexing only); per-o the 9
// per-tap maxes are masked with cndmask -> -inf before the tree max.
// ---------------------------------------------------------------------------
__global__ __launch_bounds__(256) void stage2_kernel(
    const float* __restrict__ y, const float* __restrict__ w,
    float* __restrict__ out) {
  int gid = blockIdx.x * blockDim.x + threadIdx.x;
  const int total = B_ * OH * OW;
  if (gid >= total) return;
  int j = gid % OW;
  int t2 = gid / OW;
  int i = t2 % OH;
  int b = t2 / OH;

  // clamped neighbor indices (always in-bounds loads; invalid taps masked later)
  bool v1h = (i + 1) < OH, v2h = (i + 2) < OH;
  bool v1w = (j + 1) < OW, v2w = (j + 2) < OW;
  int i1 = v1h ? i + 1 : i, i2 = v2h ? i + 2 : i;
  int j1 = v1w ? j + 1 : j, j2 = v2w ? j + 2 : j;

  const float* yb = y + (long)b * CIN * (OH * OW);
  float tv[CIN][9];
#pragma unroll
  for (int c = 0; c < CIN; ++c) {
    const float* yc = yb + c * (OH * OW);
    const float* r0 = yc + i  * OW;
    const float* r1 = yc + i1 * OW;
    const float* r2 = yc + i2 * OW;
    tv[c][0] = r0[j];  tv[c][1] = r0[j1]; tv[c][2] = r0[j2];
    tv[c][3] = r1[j];  tv[c][4] = r1[j1]; tv[c][5] = r1[j2];
    tv[c][6] = r2[j];  tv[c][7] = r2[j1]; tv[c][8] = r2[j2];
  }

  // tap validity, index tkk = kh*3+kw
  bool vt1 = v1w, vt2 = v2w;
  bool vt3 = v1h, vt4 = v1h && v1w, vt5 = v1h && v2w;
  bool vt6 = v2h, vt7 = v2h && v1w, vt8 = v2h && v2w;

  const float NEG_INF = -__builtin_inff();
  float mn = __builtin_inff();

  for (int o = 0; o < COUT; ++o) {
    float m[9];
#pragma unroll
    for (int k = 0; k < 9; ++k) m[k] = NEG_INF;
#pragma unroll
    for (int c = 0; c < CIN; ++c) {
      const float* wp = w + (o * CIN + c) * 9;  // wave-uniform -> s_load
#pragma unroll
      for (int k = 0; k < 9; ++k) {
        m[k] = fmaxf(m[k], tv[c][k] * wp[k]);
      }
    }
    // mask invalid taps, then tree-max
    float mx = m[0];
    mx = fmaxf(mx, vt1 ? m[1] : NEG_INF);
    mx = fmaxf(mx, vt2 ? m[2] : NEG_INF);
    mx = fmaxf(mx, vt3 ? m[3] : NEG_INF);
    mx = fmaxf(mx, vt4 ? m[4] : NEG_INF);
    mx = fmaxf(mx, vt5 ? m[5] : NEG_INF);
    mx = fmaxf(mx, vt6 ? m[6] : NEG_INF);
    mx = fmaxf(mx, vt7 ? m[7] : NEG_INF);
    mx = fmaxf(mx, vt8 ? m[8] : NEG_INF);
    mn = fminf(mn, mx);
  }

  out[gid] = 2.0f * mn;
}

extern "C" void kernel_launch(void* const* d_in, const int* in_sizes, int n_in,
                              void* d_out, int out_size, void* d_ws, size_t ws_size,
                              hipStream_t stream) {
  const float* x    = (const float*)d_in[0];  // (8,8,128,128)
  const float* w    = (const float*)d_in[1];  // (32,8,3,3)
  const float* bias = (const float*)d_in[2];  // (32,)
  float* out = (float*)d_out;                 // (8,1,126,126) fp32
  float* y   = (float*)d_ws;                  // needs 8*8*126*126*4 = 4.06 MB

  const int total = B_ * OH * OW;             // 127008
  const int threads = 256;
  const int blocks = (total + threads - 1) / threads;

  conv_y_kernel<<<blocks, threads, 0, stream>>>(x, w, bias, y);
  stage2_kernel<<<blocks, threads, 0, stream>>>(y, w, out);
}